// Round 5
// baseline (1236.333 us; speedup 1.0000x reference)
//
#include <hip/hip_runtime.h>
#include <cstdint>
#include <cstddef>

#define DIMX 256
#define DIMV 512
#define DIMH 768
#define EPSV 0.05f

typedef __bf16 bf16x8 __attribute__((ext_vector_type(8)));
typedef unsigned short u16x8 __attribute__((ext_vector_type(8)));
typedef unsigned int u32x4 __attribute__((ext_vector_type(4)));
typedef float f32x4 __attribute__((ext_vector_type(4)));

__device__ __forceinline__ unsigned short f2bf(float f) {
  unsigned int u = __float_as_uint(f);
  u += 0x7fffu + ((u >> 16) & 1u);
  return (unsigned short)(u >> 16);
}
__device__ __forceinline__ float bf2f(unsigned short b) {
  return __uint_as_float(((unsigned int)b) << 16);
}
__device__ __forceinline__ bf16x8 ld8(const unsigned short* p) {
  u16x8 u = *reinterpret_cast<const u16x8*>(p);
  return __builtin_bit_cast(bf16x8, u);
}
__device__ __forceinline__ f32x4 mfma16(bf16x8 a, bf16x8 b, f32x4 c) {
  return __builtin_amdgcn_mfma_f32_16x16x32_bf16(a, b, c, 0, 0, 0);
}

// ---------------- K0: split X into bf16 hi/lo for split-MFMA SYRK ----------------
__global__ void k_split(const float* __restrict__ X, unsigned short* __restrict__ Xhi,
                        unsigned short* __restrict__ Xlo) {
  int idx = blockIdx.x * 256 + threadIdx.x;
  if (idx < DIMH * DIMH) {
    float f = X[idx];
    unsigned short h = f2bf(f);
    Xhi[idx] = h;
    Xlo[idx] = f2bf(f - bf2f(h));
  }
}

// ---------------- K1: P = 0.5*Pstar@Pstar^T + eps*I (fp32, direct) ----------------
__global__ void k_syrkP(const float* __restrict__ A, float* __restrict__ P) {
  int bi = blockIdx.x >> 4, bj = blockIdx.x & 15;
  int ty = threadIdx.x >> 4, tx = threadIdx.x & 15;
  int i = bi * 16 + ty, j = bj * 16 + tx;
  const f32x4* ra = reinterpret_cast<const f32x4*>(A + (size_t)i * DIMX);
  const f32x4* rb = reinterpret_cast<const f32x4*>(A + (size_t)j * DIMX);
  float s = 0.f;
  for (int k = 0; k < 64; ++k) {
    f32x4 a = ra[k], b = rb[k];
    s = fmaf(a[0], b[0], s); s = fmaf(a[1], b[1], s);
    s = fmaf(a[2], b[2], s); s = fmaf(a[3], b[3], s);
  }
  P[(size_t)i * DIMX + j] = 0.5f * s + (i == j ? EPSV : 0.f);
}

// ---------------- K2: H = X@X^T + eps*I via bf16x2 split MFMA ----------------
__global__ __launch_bounds__(256) void k_syrkH(const unsigned short* __restrict__ Xhi,
                                               const unsigned short* __restrict__ Xlo,
                                               float* __restrict__ H) {
  int bx = blockIdx.x % 12, by = blockIdx.x / 12;
  int i0 = by * 64, j0 = bx * 64;
  int l = threadIdx.x & 63, wv = threadIdx.x >> 6;
  int lr = l & 15, lq = l >> 4;
  int koff = lq * 8;
  int arow = i0 + wv * 16 + lr;
  f32x4 z = {0.f, 0.f, 0.f, 0.f};
  f32x4 acc[4] = {z, z, z, z};
  for (int pass = 0; pass < 3; ++pass) {
    const unsigned short* Xa = (pass == 2) ? Xlo : Xhi;
    const unsigned short* Xb = (pass == 1) ? Xlo : Xhi;
    for (int kc = 0; kc < 24; ++kc) {
      bf16x8 a = ld8(&Xa[(size_t)arow * DIMH + kc * 32 + koff]);
#pragma unroll
      for (int ct = 0; ct < 4; ++ct) {
        bf16x8 b = ld8(&Xb[(size_t)(j0 + ct * 16 + lr) * DIMH + kc * 32 + koff]);
        acc[ct] = mfma16(a, b, acc[ct]);
      }
    }
  }
#pragma unroll
  for (int ct = 0; ct < 4; ++ct)
#pragma unroll
    for (int r = 0; r < 4; ++r) {
      int i = i0 + wv * 16 + lq * 4 + r;
      int j = j0 + ct * 16 + lr;
      H[(size_t)i * DIMH + j] = acc[ct][r] + (i == j ? EPSV : 0.f);
    }
}

// ---------------- K3: Pinv = inv(P) — BLOCKED (rank-32) in-place Gauss-Jordan ----------
// Round-4 post-mortem: scalar GJ was VALU-issue-bound (m[8][8] AGPR-resident; 256 iters
// x full-matrix touch = ~128 accvgpr moves + 64 fma + 64 sel per iter). Blocked rank-32
// touches each m element 8x instead of 256x. Pivot-block inverse done in-place in LDS
// (1 elem/thread, 32 micro-steps). Ut stores U^T with XOR chunk swizzle (chunk ^= tc&7)
// so the trailing update's b128 reads are <=4-way conflicts (stride 36 floats alone
// would be 32-way: 288*tc mod 32 == 0).
#define GJ_CS 36
#define GJ_RS 260
#define GJ_CALL 0
#define GJ_UT   36864
#define GJ_RALL 73728
#define GJ_DW   107008
#define GJ_SMEM 111616

__global__ __launch_bounds__(1024, 4) void k_gj256(const float* __restrict__ P,
                                                   float* __restrict__ Pinv) {
  extern __shared__ char gjs[];
  float* Call = (float*)(gjs + GJ_CALL);
  float* Ut   = (float*)(gjs + GJ_UT);
  float* Rall = (float*)(gjs + GJ_RALL);
  float* Dw   = (float*)(gjs + GJ_DW);
  int t = threadIdx.x;
  int tr = t >> 5, tc = t & 31;
  float m[8][8];
#pragma unroll
  for (int i = 0; i < 8; ++i) {
    f32x4 a = *reinterpret_cast<const f32x4*>(&P[(size_t)(8 * tr + i) * 256 + 8 * tc]);
    f32x4 b = *reinterpret_cast<const f32x4*>(&P[(size_t)(8 * tr + i) * 256 + 8 * tc + 4]);
    m[i][0] = a[0]; m[i][1] = a[1]; m[i][2] = a[2]; m[i][3] = a[3];
    m[i][4] = b[0]; m[i][5] = b[1]; m[i][6] = b[2]; m[i][7] = b[3];
  }

#pragma unroll 1
  for (int s = 0; s < 8; ++s) {
    // P1: stage column panel Call[256][32] = m[:,K] and row panel Rall[32][256] = m[K,:]
    if ((tc >> 2) == s) {
      int cl0 = (tc & 3) * 8;
#pragma unroll
      for (int i = 0; i < 8; ++i) {
        f32x4 a = {m[i][0], m[i][1], m[i][2], m[i][3]};
        f32x4 b = {m[i][4], m[i][5], m[i][6], m[i][7]};
        *reinterpret_cast<f32x4*>(&Call[(8 * tr + i) * GJ_CS + cl0]) = a;
        *reinterpret_cast<f32x4*>(&Call[(8 * tr + i) * GJ_CS + cl0 + 4]) = b;
      }
    }
    if ((tr >> 2) == s) {
#pragma unroll
      for (int i = 0; i < 8; ++i) {
        int rl = 8 * (tr & 3) + i;
        f32x4 a = {m[i][0], m[i][1], m[i][2], m[i][3]};
        f32x4 b = {m[i][4], m[i][5], m[i][6], m[i][7]};
        *reinterpret_cast<f32x4*>(&Rall[rl * GJ_RS + 8 * tc]) = a;
        *reinterpret_cast<f32x4*>(&Rall[rl * GJ_RS + 8 * tc + 4]) = b;
      }
    }
    __syncthreads();

    // P2: Dw = pivot block; in-place GJ inverse, 1 element per thread (i=tr, j=tc)
    Dw[tr * GJ_CS + tc] = Call[(32 * s + tr) * GJ_CS + tc];
    __syncthreads();
#pragma unroll 1
    for (int k = 0; k < 32; ++k) {
      float dkk = Dw[k * GJ_CS + k];
      float aik = Dw[tr * GJ_CS + k];
      float akj = Dw[k * GJ_CS + tc];
      float dij = Dw[tr * GJ_CS + tc];
      float ip = 1.0f / dkk;
      __syncthreads();
      float nv;
      if (tr == k) nv = (tc == k) ? ip : ip * akj;
      else         nv = (tc == k) ? -aik * ip : fmaf(-aik * ip, akj, dij);
      Dw[tr * GJ_CS + tc] = nv;
      __syncthreads();
    }

    // P3: U'[kk][c] = (Dinv @ Rall)[kk][c] for c notin K, = Dinv[kk][c-32s] for c in K.
    // Stored transposed+swizzled: Ut[c][chunk g (kk 4g..4g+3)] at chunk pos g ^ ((c>>3)&7).
    {
      int c = t & 255, g = t >> 8, q0 = g * 8;
      int sw = (c >> 3) & 7;
      float r0_ = 0.f, r1_ = 0.f, r2_ = 0.f, r3_ = 0.f;
      float r4_ = 0.f, r5_ = 0.f, r6_ = 0.f, r7_ = 0.f;
      if ((c >> 5) == s) {
        int jl = c & 31;
        r0_ = Dw[(q0 + 0) * GJ_CS + jl]; r1_ = Dw[(q0 + 1) * GJ_CS + jl];
        r2_ = Dw[(q0 + 2) * GJ_CS + jl]; r3_ = Dw[(q0 + 3) * GJ_CS + jl];
        r4_ = Dw[(q0 + 4) * GJ_CS + jl]; r5_ = Dw[(q0 + 5) * GJ_CS + jl];
        r6_ = Dw[(q0 + 6) * GJ_CS + jl]; r7_ = Dw[(q0 + 7) * GJ_CS + jl];
      } else {
#pragma unroll 1
        for (int kk = 0; kk < 32; ++kk) {
          float rv = Rall[kk * GJ_RS + c];
          r0_ = fmaf(Dw[(q0 + 0) * GJ_CS + kk], rv, r0_);
          r1_ = fmaf(Dw[(q0 + 1) * GJ_CS + kk], rv, r1_);
          r2_ = fmaf(Dw[(q0 + 2) * GJ_CS + kk], rv, r2_);
          r3_ = fmaf(Dw[(q0 + 3) * GJ_CS + kk], rv, r3_);
          r4_ = fmaf(Dw[(q0 + 4) * GJ_CS + kk], rv, r4_);
          r5_ = fmaf(Dw[(q0 + 5) * GJ_CS + kk], rv, r5_);
          r6_ = fmaf(Dw[(q0 + 6) * GJ_CS + kk], rv, r6_);
          r7_ = fmaf(Dw[(q0 + 7) * GJ_CS + kk], rv, r7_);
        }
      }
      f32x4 w0 = {r0_, r1_, r2_, r3_};
      f32x4 w1 = {r4_, r5_, r6_, r7_};
      *reinterpret_cast<f32x4*>(&Ut[c * GJ_CS + 4 * ((2 * g) ^ sw)]) = w0;
      *reinterpret_cast<f32x4*>(&Ut[c * GJ_CS + 4 * ((2 * g + 1) ^ sw)]) = w1;
    }
    __syncthreads();

    // P4: generic rank-32 update m -= Call_rows . U'_cols
#pragma unroll
    for (int kkg = 0; kkg < 8; ++kkg) {
      f32x4 Cv[8];
#pragma unroll
      for (int i = 0; i < 8; ++i)
        Cv[i] = *reinterpret_cast<const f32x4*>(&Call[(8 * tr + i) * GJ_CS + 4 * kkg]);
#pragma unroll
      for (int j = 0; j < 8; ++j) {
        int cc = 8 * tc + j;
        f32x4 Uv = *reinterpret_cast<const f32x4*>(&Ut[cc * GJ_CS + 4 * (kkg ^ (tc & 7))]);
#pragma unroll
        for (int i = 0; i < 8; ++i) {
          m[i][j] = fmaf(-Cv[i][0], Uv[0], m[i][j]);
          m[i][j] = fmaf(-Cv[i][1], Uv[1], m[i][j]);
          m[i][j] = fmaf(-Cv[i][2], Uv[2], m[i][j]);
          m[i][j] = fmaf(-Cv[i][3], Uv[3], m[i][j]);
        }
      }
    }
    // fixup pivot-col block: m_new = -C.Dinv = (generic result) - Call_old
    if ((tc >> 2) == s) {
      int cl0 = (tc & 3) * 8;
#pragma unroll
      for (int i = 0; i < 8; ++i)
#pragma unroll
        for (int j = 0; j < 8; ++j)
          m[i][j] -= Call[(8 * tr + i) * GJ_CS + cl0 + j];
    }
    // fixup pivot-row block: m_new = U' rows (K-cols of Ut hold Dinv, so m[K][K]=Dinv)
    if ((tr >> 2) == s) {
#pragma unroll
      for (int i = 0; i < 8; ++i) {
        int rl = 8 * (tr & 3) + i;
#pragma unroll
        for (int j = 0; j < 8; ++j) {
          int cc = 8 * tc + j;
          m[i][j] = Ut[cc * GJ_CS + 4 * ((rl >> 2) ^ (tc & 7)) + (rl & 3)];
        }
      }
    }
    __syncthreads();
  }

#pragma unroll
  for (int i = 0; i < 8; ++i) {
    f32x4 a = {m[i][0], m[i][1], m[i][2], m[i][3]};
    f32x4 b = {m[i][4], m[i][5], m[i][6], m[i][7]};
    *reinterpret_cast<f32x4*>(&Pinv[(size_t)(8 * tr + i) * 256 + 8 * tc]) = a;
    *reinterpret_cast<f32x4*>(&Pinv[(size_t)(8 * tr + i) * 256 + 8 * tc + 4]) = b;
  }
}

// ---------------- K4: Gin[c][q] = [C1 | D11] as bf16 ----------------
__global__ void k_gin(const float* __restrict__ H, const float* __restrict__ Chi,
                      unsigned short* __restrict__ Gin) {
  int q = blockIdx.x * 256 + threadIdx.x;
  int c = blockIdx.y;
  float rlam = 2.f / H[(size_t)(256 + c) * DIMH + 256 + c];
  float v;
  if (q < 256) {
    v = Chi[(size_t)q * DIMV + c] * rlam;
  } else {
    int j = q - 256;
    v = (j < c) ? -H[(size_t)(256 + c) * DIMH + 256 + j] * rlam : 0.f;
  }
  Gin[(size_t)c * DIMH + q] = f2bf(v);
}

// ---------------- K5: Gout = Pinv @ [Y | M] as bf16 ----------------
__global__ __launch_bounds__(256) void k_gout(const float* __restrict__ Pinv,
                                              const float* __restrict__ H,
                                              const float* __restrict__ Y1,
                                              const float* __restrict__ Chi,
                                              unsigned short* __restrict__ Gout) {
  __shared__ float Ps[32][33], Bs[32][33];
  int q0 = blockIdx.x * 32, i0 = blockIdx.y * 32;
  int t = threadIdx.x;
  int tx = t & 31, ty = t >> 5;
  int lrr = t >> 3, lc4 = (t & 7) * 4;
  float acc[4] = {0.f, 0.f, 0.f, 0.f};
  for (int kc = 0; kc < 8; ++kc) {
    int k0 = kc * 32;
    f32x4 pv = *reinterpret_cast<const f32x4*>(&Pinv[(size_t)(i0 + lrr) * 256 + k0 + lc4]);
    Ps[lrr][lc4 + 0] = pv[0]; Ps[lrr][lc4 + 1] = pv[1];
    Ps[lrr][lc4 + 2] = pv[2]; Ps[lrr][lc4 + 3] = pv[3];
    int k = k0 + lrr;
#pragma unroll
    for (int e = 0; e < 4; ++e) {
      int q = q0 + lc4 + e;
      float v;
      if (q < 256) {
        v = -0.5f * (H[(size_t)k * DIMH + q] + Y1[(size_t)k * 256 + q] - Y1[(size_t)q * 256 + k]);
      } else {
        int c = q - 256;
        v = -(H[(size_t)k * DIMH + 256 + c] + Chi[(size_t)k * DIMV + c]);
      }
      Bs[lrr][lc4 + e] = v;
    }
    __syncthreads();
#pragma unroll
    for (int kk = 0; kk < 32; ++kk) {
      float bb = Bs[kk][tx];
#pragma unroll
      for (int rr = 0; rr < 4; ++rr) acc[rr] = fmaf(Ps[4 * ty + rr][kk], bb, acc[rr]);
    }
    __syncthreads();
  }
#pragma unroll
  for (int rr = 0; rr < 4; ++rr)
    Gout[(size_t)(i0 + 4 * ty + rr) * DIMH + q0 + tx] = f2bf(acc[rr]);
}

// ---------------- K6: fused main v3 — [x|w] A-operand entirely in registers ----------------
// (unchanged this round: counters surface next profile as top dispatch)
#define ACCSTR 33
#define ACC_W 4224
#define DD_W 2048
#define WT_W 2560
#define SMEM_MAIN (4 * (ACC_W + DD_W + WT_W))

__global__ __launch_bounds__(256, 2) void k_main(const float* __restrict__ x,
                                                 const unsigned short* __restrict__ Gin,
                                                 const unsigned short* __restrict__ Gout,
                                                 const float* __restrict__ bv,
                                                 const float* __restrict__ bx,
                                                 float* __restrict__ out) {
  extern __shared__ char smem[];
  int tid = threadIdx.x;
  int wv = tid >> 6, l = tid & 63;
  int lr = l & 15, lq = l >> 4, koff = lq * 8;
  float* accb = (float*)(smem + wv * ACC_W);
  char* ddiag = smem + 4 * ACC_W + wv * DD_W;
  char* wtmp = smem + 4 * ACC_W + 4 * DD_W + wv * WT_W;

  int rowbase = blockIdx.x * 128 + wv * 32;

  bf16x8 frag0[24], frag1[24];
  {
    u16x8 zz = {0, 0, 0, 0, 0, 0, 0, 0};
#pragma unroll
    for (int c = 8; c < 24; ++c) {
      frag0[c] = __builtin_bit_cast(bf16x8, zz);
      frag1[c] = __builtin_bit_cast(bf16x8, zz);
    }
  }
#pragma unroll
  for (int kc = 0; kc < 8; ++kc) {
    const float* xr0 = x + (size_t)(rowbase + lr) * 256 + koff + kc * 32;
    const float* xr1 = x + (size_t)(rowbase + 16 + lr) * 256 + koff + kc * 32;
    f32x4 a0 = *reinterpret_cast<const f32x4*>(xr0);
    f32x4 a1 = *reinterpret_cast<const f32x4*>(xr0 + 4);
    f32x4 b0 = *reinterpret_cast<const f32x4*>(xr1);
    f32x4 b1 = *reinterpret_cast<const f32x4*>(xr1 + 4);
    u16x8 u0, u1;
#pragma unroll
    for (int e = 0; e < 4; ++e) {
      u0[e] = f2bf(a0[e]); u0[4 + e] = f2bf(a1[e]);
      u1[e] = f2bf(b0[e]); u1[4 + e] = f2bf(b1[e]);
    }
    frag0[kc] = __builtin_bit_cast(bf16x8, u0);
    frag1[kc] = __builtin_bit_cast(bf16x8, u1);
  }

  f32x4 z = {0.f, 0.f, 0.f, 0.f};

#pragma unroll 1
  for (int b = 0; b < 16; ++b) {
#pragma unroll
    for (int t = 0; t < 2; ++t) {
      int row = t * 16 + (l >> 2);
      const unsigned short* src =
          Gin + (size_t)(32 * b + row) * DIMH + 256 + 32 * b + (l & 3) * 8;
      u16x8 v = *reinterpret_cast<const u16x8*>(src);
      *reinterpret_cast<u16x8*>(ddiag + t * 1024 + l * 16) = v;
    }

    f32x4 a00 = z, a01 = z, a10 = z, a11 = z;
    const unsigned short* gb0 = Gin + (size_t)(32 * b + lr) * DIMH + koff;
    const unsigned short* gb1 = gb0 + 16 * DIMH;
#pragma unroll
    for (int g = 0; g < 6; ++g) {
      if (g * 4 < 8 + b) {
#pragma unroll
        for (int cc = 0; cc < 4; ++cc) {
          int c = g * 4 + cc;
          bf16x8 bb0 = ld8(gb0 + c * 32);
          bf16x8 bb1 = ld8(gb1 + c * 32);
          a00 = mfma16(frag0[c], bb0, a00);
          a01 = mfma16(frag0[c], bb1, a01);
          a10 = mfma16(frag1[c], bb0, a10);
          a11 = mfma16(frag1[c], bb1, a11);
        }
      }
    }

    float bv0 = bv[32 * b + lr], bv1 = bv[32 * b + 16 + lr];
#pragma unroll
    for (int r = 0; r < 4; ++r) {
      accb[(lq * 4 + r) * ACCSTR + lr] = a00[r] + bv0;
      accb[(lq * 4 + r) * ACCSTR + 16 + lr] = a01[r] + bv1;
      accb[(16 + lq * 4 + r) * ACCSTR + lr] = a10[r] + bv0;
      accb[(16 + lq * 4 + r) * ACCSTR + 16 + lr] = a11[r] + bv1;
    }

    if (l < 32) {
      const unsigned int* dd = (const unsigned int*)ddiag;
      float wf[32];
      unsigned int wpk[16];
#pragma unroll
      for (int i = 0; i < 32; ++i) {
        float p0 = 0.f, p1 = 0.f;
        const unsigned int* ddr = dd + i * 16;
#pragma unroll
        for (int j = 0; j < i; ++j) {
          unsigned int pw = ddr[j >> 1];
          float dj = __uint_as_float((j & 1) ? (pw & 0xffff0000u) : (pw << 16));
          if (j & 1) p1 = fmaf(dj, wf[j], p1);
          else       p0 = fmaf(dj, wf[j], p0);
        }
        float s = accb[l * ACCSTR + i] + p0 + p1;
        s = fminf(fmaxf(s, -12.f), 12.f);
        float e = __expf(2.f * s);
        float w = (e - 1.f) * __builtin_amdgcn_rcpf(e + 1.f);
        wf[i] = w;
        unsigned int hb = (unsigned int)f2bf(w);
        if (i & 1) wpk[i >> 1] |= hb << 16;
        else       wpk[i >> 1] = hb;
      }
      u32x4* wp = (u32x4*)(wtmp + l * 80);
      u32x4 w0 = {wpk[0], wpk[1], wpk[2], wpk[3]};     wp[0] = w0;
      u32x4 w1 = {wpk[4], wpk[5], wpk[6], wpk[7]};     wp[1] = w1;
      u32x4 w2 = {wpk[8], wpk[9], wpk[10], wpk[11]};   wp[2] = w2;
      u32x4 w3 = {wpk[12], wpk[13], wpk[14], wpk[15]}; wp[3] = w3;
    }

    bf16x8 nw0 = ld8((const unsigned short*)(wtmp + lr * 80 + lq * 16));
    bf16x8 nw1 = ld8((const unsigned short*)(wtmp + (16 + lr) * 80 + lq * 16));
#pragma unroll
    for (int j = 0; j < 16; ++j) {
      if (b == j) { frag0[8 + j] = nw0; frag1[8 + j] = nw1; }
    }
  }

#pragma unroll 1
  for (int ct = 0; ct < 16; ++ct) {
    f32x4 o0 = z, o1 = z;
    const unsigned short* gg = Gout + (size_t)(ct * 16 + lr) * DIMH + koff;
#pragma unroll
    for (int c = 0; c < 24; ++c) {
      bf16x8 bb = ld8(gg + c * 32);
      o0 = mfma16(frag0[c], bb, o0);
      o1 = mfma16(frag1[c], bb, o1);
    }
    float bxv = bx[ct * 16 + lr];
#pragma unroll
    for (int r = 0; r < 4; ++r) {
      out[(size_t)(rowbase + lq * 4 + r) * 256 + ct * 16 + lr] = o0[r] + bxv;
      out[(size_t)(rowbase + 16 + lq * 4 + r) * 256 + ct * 16 + lr] = o1[r] + bxv;
    }
  }
}

extern "C" void kernel_launch(void* const* d_in, const int* in_sizes, int n_in,
                              void* d_out, int out_size, void* d_ws, size_t ws_size,
                              hipStream_t stream) {
  const float* x   = (const float*)d_in[1];
  const float* Pst = (const float*)d_in[2];
  const float* Chi = (const float*)d_in[3];
  const float* X   = (const float*)d_in[4];
  const float* Y1  = (const float*)d_in[5];
  const float* bv  = (const float*)d_in[8];
  const float* bx  = (const float*)d_in[9];
  float* out = (float*)d_out;

  char* ws = (char*)d_ws;
  const size_t OFF_H    = 0;
  const size_t OFF_P    = 2359296;
  const size_t OFF_PINV = 2621440;
  const size_t OFF_XHI  = 2883584;
  const size_t OFF_XLO  = 4063232;
  const size_t OFF_GIN  = 5242880;
  const size_t OFF_GOUT = 6029312;
  if (ws_size < 6422528) return;

  float* H    = (float*)(ws + OFF_H);
  float* P    = (float*)(ws + OFF_P);
  float* Pinv = (float*)(ws + OFF_PINV);
  unsigned short* Xhi  = (unsigned short*)(ws + OFF_XHI);
  unsigned short* Xlo  = (unsigned short*)(ws + OFF_XLO);
  unsigned short* Gin  = (unsigned short*)(ws + OFF_GIN);
  unsigned short* Gout = (unsigned short*)(ws + OFF_GOUT);

  k_split<<<2304, 256, 0, stream>>>(X, Xhi, Xlo);
  k_syrkP<<<256, 256, 0, stream>>>(Pst, P);
  k_syrkH<<<144, 256, 0, stream>>>(Xhi, Xlo, H);
  k_gj256<<<1, 1024, GJ_SMEM, stream>>>(P, Pinv);
  dim3 gg(3, 512);
  k_gin<<<gg, 256, 0, stream>>>(H, Chi, Gin);
  dim3 go(24, 8);
  k_gout<<<go, 256, 0, stream>>>(Pinv, H, Y1, Chi, Gout);
  k_main<<<512, 256, SMEM_MAIN, stream>>>(x, Gin, Gout, bv, bx, out);
}